// Round 4
// baseline (1220.600 us; speedup 1.0000x reference)
//
#include <hip/hip_runtime.h>

// MultiLoRALinear: out = x @ (W + sum_n sc_n*mag_n*(up_n @ down_n))^T + b
// R6: remove intra-tile barriers + software-pipeline fragment reads.
// R5 post-mortem: conflicts 5e7->0 but MfmaUtil stuck at 32% -- the
// double-barrier-per-phase lockstep alternates {all-waves ds_read burst}
// with {all-waves MFMA burst}; LDS and matrix pipes never overlap
// (4 x (770+620) cyc ~= observed 7760 cyc/tile vs 2480 MFMA-only).
// New tile body: reads for phase p+1 issue before MFMA of phase p (plain
// C++, compiler emits precise counted lgkmcnt); ONE __syncthreads per
// K-tile. Its implicit vmcnt(0) only drains next-tile loads issued a full
// tile earlier (free). Stage targets opposite buffer -> no intra-tile race.
// Swizzles (LDS XOR chunk + XCD block) and epilogue unchanged from R5.

#define B_DIM 4
#define S_DIM 4096
#define IND   4096
#define OUTD  4096
#define NADP  8
#define RK    64
#define MROWS (B_DIM * S_DIM)
#define KADAPT (NADP * RK)

typedef __attribute__((ext_vector_type(8))) short short8;
typedef __attribute__((ext_vector_type(8))) unsigned short ushort8;
typedef __attribute__((ext_vector_type(4))) float float4v;

__device__ __forceinline__ unsigned short f2bf(float f) {
  unsigned int u = __builtin_bit_cast(unsigned int, f);
  u += 0x7FFFu + ((u >> 16) & 1u);
  return (unsigned short)(u >> 16);
}

__global__ void fold_up_k(const float* __restrict__ ups, const float* __restrict__ mags,
                          const float* __restrict__ scales, unsigned short* __restrict__ up_eff) {
  int tid = blockIdx.x * 256 + threadIdx.x;
  int o  = tid >> 9;
  int nr = tid & 511;
  int n  = nr >> 6;
  int r  = nr & 63;
  float v = ups[((size_t)n * OUTD + o) * RK + r] * mags[n * OUTD + o] * scales[n];
  up_eff[tid] = f2bf(v);
}

__global__ void tdown_k(const float* __restrict__ downs, unsigned short* __restrict__ dT) {
  int tid = blockIdx.x * 256 + threadIdx.x;
  int i  = tid >> 9;
  int nr = tid & 511;
  dT[tid] = f2bf(downs[(size_t)nr * IND + i]);
}

__global__ void cvt_x_k(const float* __restrict__ x, unsigned short* __restrict__ xb) {
  int tid = blockIdx.x * 256 + threadIdx.x;
  const float4v* xv = (const float4v*)x;
  float4v a = xv[2 * tid];
  float4v b = xv[2 * tid + 1];
  ushort8 o;
  o[0] = f2bf(a[0]); o[1] = f2bf(a[1]); o[2] = f2bf(a[2]); o[3] = f2bf(a[3]);
  o[4] = f2bf(b[0]); o[5] = f2bf(b[1]); o[6] = f2bf(b[2]); o[7] = f2bf(b[3]);
  ((ushort8*)xb)[tid] = o;
}

#define GLOAD_LDS16(g, l)                                                        \
  __builtin_amdgcn_global_load_lds((const __attribute__((address_space(1))) void*)(g), \
                                   (__attribute__((address_space(3))) void*)(l), 16, 0, 0)

// NT GEMM: C[m,n] = sum_k A[m,k]*B[n,k], A:[M,K] B:[N,K] bf16 row-major.
// BM=BN=256, BK=64 (2 x 32-wide k-slices), 512 threads (8 waves, 2x4).
// LDS region per k-slice: [256][32] bf16 (64B rows). Slot [row][kq] holds
// global 16B chunk kq ^ ((row>>1)&3) -> ds_read_b128 is 2-way-aliased (free).
template <int EPI>
__global__ __launch_bounds__(512, 2) void gemm256(const unsigned short* __restrict__ A,
                                                  const unsigned short* __restrict__ B,
                                                  const float* __restrict__ extra,
                                                  void* __restrict__ Cout,
                                                  int M, int N, int K) {
  __shared__ __align__(16) unsigned short As[2][2][256 * 32];  // 64 KB
  __shared__ __align__(16) unsigned short Bs[2][2][256 * 32];  // 64 KB

  const int tid  = threadIdx.x;
  const int lane = tid & 63;
  const int w    = tid >> 6;
  const int wm   = w >> 2;
  const int wn   = w & 3;
  const int qr   = lane & 15;
  // read-side swizzle: global chunk (lane>>4) of row r sits at slot
  // (lane>>4) ^ ((r>>1)&3);  r mod 16 == qr for every fragment row.
  const int ks   = (((lane >> 4) ^ ((qr >> 1) & 3))) * 8;

  const int nwg  = gridDim.x * gridDim.y;
  const int orig = blockIdx.y * gridDim.x + blockIdx.x;
  const int cpx  = nwg >> 3;
  const int swz  = (orig & 7) * cpx + (orig >> 3);
  const int bm   = swz / gridDim.y;
  const int bn   = swz % gridDim.y;

  const size_t Kz = (size_t)K;
  // stage-side swizzle: lane l writes LDS slot l*16B = [lrow][l&3]; source it
  // from global chunk (l&3) ^ ((lrow>>1)&3) so the slot invariant holds.
  const int lrow = lane >> 2;
  const int lk   = (((lane & 3) ^ ((lrow >> 1) & 3))) * 8;
  const unsigned short* aSrc = A + ((size_t)bm * 256 + w * 32 + lrow) * Kz + lk;
  const unsigned short* bSrc = B + ((size_t)bn * 256 + w * 32 + lrow) * Kz + lk;
  const size_t seg1 = 16 * Kz;

  unsigned short* aB = &As[0][0][0];
  unsigned short* bB = &Bs[0][0][0];

#define STAGE(SRC, DST)                                 \
  do {                                                  \
    GLOAD_LDS16((SRC), (DST) + w * 1024);               \
    GLOAD_LDS16((SRC) + seg1, (DST) + w * 1024 + 512);  \
  } while (0)

  // fragment reads: MH = m-half (0/1), KSOFF = 0 (k-lo) or 8192 (k-hi)
#define RD_A(DST, BUFP, MH, KSOFF)                                                        \
  {                                                                                       \
    _Pragma("unroll") for (int fm = 0; fm < 4; ++fm)                                      \
      DST[fm] = *(const short8*)((BUFP) + (KSOFF) +                                       \
                                 (wm * 128 + ((MH) * 4 + fm) * 16 + qr) * 32 + ks);       \
  }

#define RD_B(DST, BUFP, KSOFF)                                                            \
  {                                                                                       \
    _Pragma("unroll") for (int fn = 0; fn < 4; ++fn)                                      \
      DST[fn] = *(const short8*)((BUFP) + (KSOFF) +                                       \
                                 (wn * 64 + fn * 16 + qr) * 32 + ks);                     \
  }

#define MM(MH, AREG, BREG)                                                                \
  {                                                                                       \
    _Pragma("unroll") for (int fm = 0; fm < 4; ++fm)                                      \
      _Pragma("unroll") for (int fn = 0; fn < 4; ++fn)                                    \
        acc[(MH) * 4 + fm][fn] = __builtin_amdgcn_mfma_f32_16x16x32_bf16(                 \
            AREG[fm], BREG[fn], acc[(MH) * 4 + fm][fn], 0, 0, 0);                         \
  }

  // One K-tile: stage t+1 early (opposite buffer), pipeline reads one
  // phase ahead of MFMA, single sync at the end. Phase order per tile:
  // (mh0,klo) (mh1,klo) (mh0,khi) (mh1,khi) -- same acc k-order as before.
#define TILE(CA, CB, NXA, NXB, DOSTAGE)                 \
  do {                                                  \
    if (DOSTAGE) {                                      \
      STAGE(aSrc + 64, NXA);                            \
      STAGE(bSrc + 64, NXB);                            \
      STAGE(aSrc + 96, (NXA) + 8192);                   \
      STAGE(bSrc + 96, (NXB) + 8192);                   \
    }                                                   \
    RD_A(a0, CA, 0, 0);                                 \
    RD_B(b0, CB, 0);                                    \
    RD_A(a1, CA, 1, 0);                                 \
    MM(0, a0, b0);                                      \
    RD_A(a0, CA, 0, 8192);                              \
    RD_B(b1, CB, 8192);                                 \
    MM(1, a1, b0);                                      \
    RD_A(a1, CA, 1, 8192);                              \
    MM(0, a0, b1);                                      \
    MM(1, a1, b1);                                      \
    __syncthreads();                                    \
    aSrc += 64;                                         \
    bSrc += 64;                                         \
  } while (0)

  float4v acc[8][4] = {};
  short8 a0[4], a1[4], b0[4], b1[4];

  const int NT = K >> 6;  // K-tiles of 64; NT is even (64 or 8)

  // prologue: stage tile 0 into buf0 (klo + khi), wait, sync
  STAGE(aSrc, aB);
  STAGE(bSrc, bB);
  STAGE(aSrc + 32, aB + 8192);
  STAGE(bSrc + 32, bB + 8192);
  __syncthreads();

  for (int t2 = 0; t2 < NT - 2; t2 += 2) {
    TILE(aB,         bB,         aB + 16384, bB + 16384, true);
    TILE(aB + 16384, bB + 16384, aB,         bB,         true);
  }
  TILE(aB,         bB,         aB + 16384, bB + 16384, true);
  TILE(aB + 16384, bB + 16384, aB,         bB,         false);

  // epilogue: C/D layout col = lane&15, row = (lane>>4)*4 + reg
  if (EPI == 0) {
    float* C = (float*)Cout;
#pragma unroll
    for (int fn = 0; fn < 4; ++fn) {
      const int col = bn * 256 + wn * 64 + fn * 16 + qr;
      const float bias = extra[col];
#pragma unroll
      for (int fm = 0; fm < 8; ++fm) {
        const int rbase = bm * 256 + wm * 128 + fm * 16 + (lane >> 4) * 4;
#pragma unroll
        for (int r2 = 0; r2 < 4; ++r2)
          C[(size_t)(rbase + r2) * N + col] = acc[fm][fn][r2] + bias;
      }
    }
  } else {
    unsigned short* C = (unsigned short*)Cout;
#pragma unroll
    for (int fn = 0; fn < 4; ++fn) {
      const int col = bn * 256 + wn * 64 + fn * 16 + qr;
#pragma unroll
      for (int fm = 0; fm < 8; ++fm) {
        const int rbase = bm * 256 + wm * 128 + fm * 16 + (lane >> 4) * 4;
#pragma unroll
        for (int r2 = 0; r2 < 4; ++r2) {
          const size_t idx = (size_t)(rbase + r2) * N + col;
          C[idx] = f2bf(acc[fm][fn][r2] + extra[idx]);
        }
      }
    }
  }

#undef STAGE
#undef RD_A
#undef RD_B
#undef MM
#undef TILE
}

extern "C" void kernel_launch(void* const* d_in, const int* in_sizes, int n_in,
                              void* d_out, int out_size, void* d_ws, size_t ws_size,
                              hipStream_t stream) {
  const float* x      = (const float*)d_in[0];
  const float* W      = (const float*)d_in[1];
  const float* b      = (const float*)d_in[2];
  const float* downs  = (const float*)d_in[3];
  const float* ups    = (const float*)d_in[4];
  const float* mags   = (const float*)d_in[5];
  const float* scales = (const float*)d_in[6];
  float* out = (float*)d_out;

  char* ws = (char*)d_ws;
  unsigned short* x_bf   = (unsigned short*)ws;
  unsigned short* w_eff  = (unsigned short*)(ws + 134217728ull);
  unsigned short* up_eff = (unsigned short*)(ws + 134217728ull + 33554432ull);
  unsigned short* dT     = (unsigned short*)(ws + 134217728ull + 33554432ull + 4194304ull);

  fold_up_k<<<dim3((OUTD * KADAPT) / 256), dim3(256), 0, stream>>>(ups, mags, scales, up_eff);
  tdown_k<<<dim3((IND * KADAPT) / 256), dim3(256), 0, stream>>>(downs, dT);
  cvt_x_k<<<dim3((MROWS * IND / 8) / 256), dim3(256), 0, stream>>>(x, x_bf);

  // W_eff = bf16(W + UpEff @ DownsT)   [OUTD, IND], K=512 (NT=8)
  gemm256<1><<<dim3(OUTD / 256, IND / 256), dim3(512), 0, stream>>>(
      up_eff, dT, W, (void*)w_eff, OUTD, IND, KADAPT);

  // out = x_bf @ W_eff^T + b   [MROWS, OUTD] fp32, K=4096 (NT=64)
  gemm256<0><<<dim3(MROWS / 256, OUTD / 256), dim3(512), 0, stream>>>(
      x_bf, w_eff, b, (void*)out, MROWS, OUTD, IND);
}